// Round 4
// baseline (266.188 us; speedup 1.0000x reference)
//
#include <hip/hip_runtime.h>
#include <hip/hip_bf16.h>
#include <stdint.h>

typedef __attribute__((ext_vector_type(4))) float f32x4;
typedef __attribute__((ext_vector_type(8))) short short8;

// ---------------- geometry ----------------
#define NB 8
#define NC 512
#define HP 66
#define WP 66
#define NPOS 32768
#define KTOT 4608
#define NT 144            // K-tiles of 32

#define XP_ELEMS (NB*HP*WP*NC)
#define WR_ELEMS (NC*KTOT)
#define WC2_ELEMS (64*NC)
#define PROP_OFF 0
#define CLS_OFF  1179648
#define ANCH_OFF 1769472
#define A_PER_B  36864

__device__ __forceinline__ short bf16bits(float v) {
    __hip_bfloat16 b = __float2bfloat16(v);
    return *reinterpret_cast<short*>(&b);
}
__device__ __forceinline__ void gload16(const short* g, short* l) {
    __builtin_amdgcn_global_load_lds(
        (const __attribute__((address_space(1))) unsigned int*)g,
        (__attribute__((address_space(3))) unsigned int*)l, 16, 0, 0);
}
#define BARRIER() asm volatile("s_barrier" ::: "memory")
#define VMCNT5()  asm volatile("s_waitcnt vmcnt(5)" ::: "memory")
#define VMCNT0()  asm volatile("s_waitcnt vmcnt(0)" ::: "memory")

// ---------------- fused prep: input pack + weight packs + zero fills --------
// grid 5544: [0,4096) input; [4096,4608) conv_w; [4608,5544) misc
__global__ void prep_all(const float* __restrict__ x, const float* __restrict__ conv_w,
                         const float* __restrict__ cls_w, const float* __restrict__ reg_w,
                         short* __restrict__ Wr, short* __restrict__ Wc2,
                         short* __restrict__ Xp, float* __restrict__ out) {
    __shared__ float smem[4608];
    const int bid = blockIdx.x, tid = threadIdx.x;
    if (bid < 4096) {
        // ---- NCHW f32 -> padded NHWC bf16 (16B writes) ----
        float (*t)[65] = (float(*)[65])smem;
        const int pb = bid & 63, cb = (bid >> 6) & 7, b = bid >> 9;
        const int tx = tid & 63, ty = tid >> 6;
        const float* src = x + ((size_t)(b*NC + cb*64))*4096 + pb*64;
#pragma unroll
        for (int r = 0; r < 16; ++r) {
            int ch = ty + r*4;
            t[ch][tx] = src[(size_t)ch*4096 + tx];
        }
        __syncthreads();
#pragma unroll
        for (int rr = 0; rr < 2; ++rr) {
            int item = tid + rr*256;
            int pl = item >> 3, ck = item & 7;
            short8 v;
#pragma unroll
            for (int e = 0; e < 8; ++e) v[e] = bf16bits(t[ck*8+e][pl]);
            *(short8*)&Xp[((size_t)((b*HP + pb + 1)*WP) + (pl + 1))*NC + cb*64 + ck*8] = v;
        }
    } else if (bid < 4608) {
        // ---- conv_w OIHW f32 -> Wr[co][k*512+ci], LDS-staged ----
        const int o = bid - 4096;
        const float* src = conv_w + (size_t)o*4608;
        for (int i = tid; i < 4608; i += 256) smem[i] = src[i];
        __syncthreads();
#pragma unroll
        for (int k = 0; k < 9; ++k)
#pragma unroll
            for (int c = 0; c < 2; ++c) {
                int ci = tid + c*256;
                Wr[(size_t)o*4608 + k*512 + ci] = bf16bits(smem[ci*9 + k]);
            }
    } else {
        const int m = bid - 4608;
        if (m < 128) {
            int t = m*256 + tid;
            int row = t >> 9, ci = t & 511;
            float v = 0.f;
            if (row < 18)      v = cls_w[row*NC + ci];
            else if (row < 54) v = reg_w[(row-18)*NC + ci];
            Wc2[t] = bf16bits(v);
        } else if (m < 648) {
            int idx = (m-128)*256 + tid;          // < 133120
            int b = idx / 16640;
            int rem = idx - b*16640;
            int r = rem >> 6, g = rem & 63;
            int h, w;
            if      (r < 66)  { h = 0;       w = r; }
            else if (r < 132) { h = 65;      w = r - 66; }
            else if (r < 196) { h = r - 131; w = 0; }
            else              { h = r - 195; w = 65; }
            short8 z = (short8){0,0,0,0,0,0,0,0};
            *(short8*)&Xp[((size_t)((b*HP + h)*WP) + w)*NC + g*8] = z;
        } else {
            int idx = (m-648)*256 + tid;          // < 73728 float4s
            ((float4*)(out + ANCH_OFF))[idx] = make_float4(0.f,0.f,0.f,0.f);
        }
    }
}

// ---------------- fused: conv3x3 GEMM + 1x1 heads + anchor decode -----------
// C[p][co]: M=32768, N=512, K=4608. BM=128, BN=512, BK=32, 8 waves (2M x 4N).
// LDS 120KB: A tribuf 3x8KB @0, B tribuf 3x32KB @24KB. Stage distance t+2 on
// both A and B; steady vmcnt(5) (drains exactly {A(t+1),B(t+1)x4}).
// Epilogue reuses LDS as f_tile[128][512] bf16 (XOR-swizzled), then sm f32.
__device__ const float AW_T[9] = {
    181.01933598375618f, 362.03867196751236f, 724.0773439350247f,
    128.f, 256.f, 512.f,
    90.50966799187809f, 181.01933598375618f, 362.03867196751236f };
__device__ const float AH_T[9] = {
    90.50966799187809f, 181.01933598375618f, 362.03867196751236f,
    128.f, 256.f, 512.f,
    181.01933598375618f, 362.03867196751236f, 724.0773439350247f };

__launch_bounds__(512, 2)
__global__ void conv_fused(const short* __restrict__ Xp, const short* __restrict__ Wr,
                           const float* __restrict__ bias, const short* __restrict__ Wc2,
                           const float* __restrict__ cls_b, const float* __restrict__ reg_b,
                           const int* __restrict__ img, float* __restrict__ out) {
    extern __shared__ short lds[];
    short* ABUF[3] = {lds, lds + 4096, lds + 8192};
    short* BBUF[3] = {lds + 12288, lds + 12288 + 16384, lds + 12288 + 32768};

    const int tid = threadIdx.x;
    const int lane = tid & 63, wv = tid >> 6;
    const int bid = blockIdx.x;
    const int wg = (bid & 7) * 32 + (bid >> 3);   // XCD swizzle (256 blocks)
    const int pbase = wg * 128;
    const int wm = wv >> 2, wn = wv & 3;
    const int l15 = lane & 15, lg = lane >> 4;

    // ---- staging precompute: thread covers (row = tid>>2, slot s = tid&3)
    const int G = ((tid & 3) - (tid >> 3)) & 3;   // source k-group for slot
    int aoff;
    {
        int p = pbase + (tid >> 2);
        int b = p >> 12, h = (p >> 6) & 63, w = p & 63;
        aoff = ((b*HP + h)*WP + w)*NC + G*8;
    }
    const int boff = (tid >> 2)*KTOT + G*8;
    const int sdst = tid*8;

    // ---- read-side: sigma swizzle
    const int sigma = (((lg + ((l15 >> 1) & 3)) & 3)) * 8;

    f32x4 acc[4][8];
#pragma unroll
    for (int i = 0; i < 4; ++i)
#pragma unroll
        for (int j = 0; j < 8; ++j) acc[i][j] = (f32x4){0.f,0.f,0.f,0.f};

    short8 af_[4], bf_[8];

    auto stageA = [&](int t, short* dst) {
        int seg = t >> 4;
        int dh = seg/3, dw = seg - dh*3;
        gload16(Xp + aoff + (dh*WP + dw)*NC + (t & 15)*32, dst + sdst);
    };
    auto stageB2 = [&](int t, short* dst, int q0) {
#pragma unroll
        for (int q = q0; q < q0+2; ++q)
            gload16(Wr + boff + q*128*KTOT + t*32, dst + q*4096 + sdst);
    };
    // phA: read B frags + A frags 0..1; stage B(t+2) slots 0,1
    auto phA = [&](short* Ar, short* Br, bool sB, short* Bw, int t) {
#pragma unroll
        for (int j = 0; j < 8; ++j)
            bf_[j] = *(const short8*)(Br + (wn*128 + j*16 + l15)*32 + sigma);
#pragma unroll
        for (int ii = 0; ii < 2; ++ii)
            af_[ii] = *(const short8*)(Ar + (wm*64 + ii*16 + l15)*32 + sigma);
        if (sB) stageB2(t+2, Bw, 0);
        BARRIER();
        __builtin_amdgcn_s_setprio(1);
#pragma unroll
        for (int ii = 0; ii < 2; ++ii)
#pragma unroll
            for (int j = 0; j < 8; ++j)
                acc[ii][j] = __builtin_amdgcn_mfma_f32_16x16x32_bf16(
                    af_[ii], bf_[j], acc[ii][j], 0, 0, 0);
        __builtin_amdgcn_s_setprio(0);
        BARRIER();
    };
    // phB: read A frags 2..3; stage A(t+2) + B(t+2) slots 2,3; counted wait
    auto phB = [&](short* Ar, bool sA, short* Aw, bool sB, short* Bw, int t, int vm) {
#pragma unroll
        for (int ii = 2; ii < 4; ++ii)
            af_[ii] = *(const short8*)(Ar + (wm*64 + ii*16 + l15)*32 + sigma);
        if (sA) stageA(t+2, Aw);
        if (sB) stageB2(t+2, Bw, 2);
        BARRIER();
        __builtin_amdgcn_s_setprio(1);
#pragma unroll
        for (int ii = 2; ii < 4; ++ii)
#pragma unroll
            for (int j = 0; j < 8; ++j)
                acc[ii][j] = __builtin_amdgcn_mfma_f32_16x16x32_bf16(
                    af_[ii], bf_[j], acc[ii][j], 0, 0, 0);
        __builtin_amdgcn_s_setprio(0);
        if (vm == 5) { VMCNT5(); } else if (vm == 0) { VMCNT0(); }
        BARRIER();
    };

    // ---- prologue: queue = [B0x4, A0, B1ab, A1, B1cd]; vmcnt(5) drains B0,A0
    stageB2(0, BBUF[0], 0); stageB2(0, BBUF[0], 2);
    stageA(0, ABUF[0]);
    stageB2(1, BBUF[1], 0);
    stageA(1, ABUF[1]);
    stageB2(1, BBUF[1], 2);
    VMCNT5(); BARRIER();

    // ---- main loop: tiles 0..140 uniform (47 x 3), steady vmcnt(5)
#pragma unroll 1
    for (int itt = 0; itt < 47; ++itt) {
        const int t0 = itt*3;
#pragma unroll
        for (int c = 0; c < 3; ++c) {
            const int t = t0 + c;
            phA(ABUF[c], BBUF[c], true, BBUF[(c+2)%3], t);
            phB(ABUF[c], true, ABUF[(c+2)%3], true, BBUF[(c+2)%3], t, 5);
        }
    }
    // ---- tail: 141 (stage t+2=143, vm5), 142 (vm0), 143 (no wait)
    phA(ABUF[0], BBUF[0], true, BBUF[2], 141);
    phB(ABUF[0], true, ABUF[2], true, BBUF[2], 141, 5);
    phA(ABUF[1], BBUF[1], false, BBUF[0], 142);
    phB(ABUF[1], false, ABUF[0], false, BBUF[0], 142, 0);
    phA(ABUF[2], BBUF[2], false, BBUF[0], 143);
    phB(ABUF[2], false, ABUF[0], false, BBUF[0], 143, -1);
    __syncthreads();

    // ---- epilogue 1: bias+relu, write f_tile[128][512] bf16 (swizzled)
#pragma unroll
    for (int j = 0; j < 8; ++j) {
        const int co = wn*128 + j*16 + l15;
        const float bb = bias[co];
        const int g64 = co >> 3, e = co & 7;
#pragma unroll
        for (int i = 0; i < 4; ++i) {
#pragma unroll
            for (int r = 0; r < 4; ++r) {
                const int prow = wm*64 + i*16 + lg*4 + r;
                float v = acc[i][j][r] + bb;
                v = v > 0.f ? v : 0.f;
                const int slot = (g64 & 56) | ((g64 ^ prow) & 7);
                lds[prow*512 + slot*8 + e] = bf16bits(v);
            }
        }
    }
    __syncthreads();

    // ---- epilogue 2: head GEMM M=128,N=64,K=512
    f32x4 acc2[4];
#pragma unroll
    for (int j = 0; j < 4; ++j) acc2[j] = (f32x4){0.f,0.f,0.f,0.f};
    const int hrow = wv*16 + l15;
#pragma unroll
    for (int k0 = 0; k0 < 16; ++k0) {
        const int g64 = k0*4 + lg;
        const int slot = (g64 & 56) | ((g64 ^ hrow) & 7);
        short8 a2 = *(const short8*)&lds[hrow*512 + slot*8];
#pragma unroll
        for (int j = 0; j < 4; ++j) {
            short8 b2 = *(const short8*)&Wc2[(size_t)(j*16 + l15)*NC + k0*32 + lg*8];
            acc2[j] = __builtin_amdgcn_mfma_f32_16x16x32_bf16(a2, b2, acc2[j], 0, 0, 0);
        }
    }
    __syncthreads();

    // ---- epilogue 3: stash head outputs to sm[128][65] f32
    float* sm = (float*)lds;
    const int crow0 = wv*16 + lg*4;
#pragma unroll
    for (int j = 0; j < 4; ++j)
#pragma unroll
        for (int r = 0; r < 4; ++r)
            sm[(crow0 + r)*65 + j*16 + l15] = acc2[j][r];
    __syncthreads();

    // ---- epilogue 4: anchor decode, 128 pos x 9 anchors = 1152 items
    for (int item = tid; item < 1152; item += 512) {
        int pl = item / 9, a = item - pl*9;
        int p = pbase + pl;
        int b = p >> 12, h = (p >> 6) & 63, w = p & 63;
        float c0 = sm[pl*65 + a*2 + 0] + cls_b[a*2 + 0];
        float c1 = sm[pl*65 + a*2 + 1] + cls_b[a*2 + 1];
        float r0 = sm[pl*65 + 18 + a*4 + 0] + reg_b[a*4 + 0];
        float r1 = sm[pl*65 + 18 + a*4 + 1] + reg_b[a*4 + 1];
        float r2 = sm[pl*65 + 18 + a*4 + 2] + reg_b[a*4 + 2];
        float r3 = sm[pl*65 + 18 + a*4 + 3] + reg_b[a*4 + 3];
        float aw = AW_T[a], ah = AH_T[a];
        float ax = 8.f + 16.f*w, ay = 8.f + 16.f*h;
        float px = ax + r0*aw,  py = ay + r1*ah;
        float pw = aw*__expf(r2), ph = ah*__expf(r3);
        float imw = (float)img[b*2 + 0], imh = (float)img[b*2 + 1];
        float x1 = fminf(fmaxf(px - 0.5f*pw, 0.f), imw);
        float y1 = fminf(fmaxf(py - 0.5f*ph, 0.f), imh);
        float x2 = fminf(fmaxf(px + 0.5f*pw, 0.f), imw);
        float y2 = fminf(fmaxf(py + 0.5f*ph, 0.f), imh);
        int ag = (h*64 + w)*9 + a;
        float4* prop = (float4*)(out + PROP_OFF + ((size_t)b*A_PER_B + ag)*4);
        *prop = make_float4(x1, y1, x2, y2);
        float2* cs = (float2*)(out + CLS_OFF + ((size_t)b*A_PER_B + ag)*2);
        *cs = make_float2(c0, c1);
    }
}

extern "C" void kernel_launch(void* const* d_in, const int* in_sizes, int n_in,
                              void* d_out, int out_size, void* d_ws, size_t ws_size,
                              hipStream_t stream) {
    const float* x      = (const float*)d_in[0];
    const int*   img    = (const int*)  d_in[1];
    const float* conv_w = (const float*)d_in[2];
    const float* conv_b = (const float*)d_in[3];
    const float* cls_w  = (const float*)d_in[4];
    const float* cls_b  = (const float*)d_in[5];
    const float* reg_w  = (const float*)d_in[6];
    const float* reg_b  = (const float*)d_in[7];
    float* out = (float*)d_out;

    short* Xp  = (short*)d_ws;
    short* Wr  = Xp  + XP_ELEMS;
    short* Wc2 = Wr  + WR_ELEMS;

    prep_all<<<5544, 256, 0, stream>>>(x, conv_w, cls_w, reg_w, Wr, Wc2, Xp, out);

    hipFuncSetAttribute((const void*)conv_fused,
                        hipFuncAttributeMaxDynamicSharedMemorySize, 131072);
    conv_fused<<<256, 512, 131072, stream>>>(Xp, Wr, conv_b, Wc2,
                                             cls_b, reg_b, img, out);
}

// Round 6
// 248.144 us; speedup vs baseline: 1.0727x; 1.0727x over previous
//
#include <hip/hip_runtime.h>
#include <hip/hip_bf16.h>
#include <stdint.h>

typedef __attribute__((ext_vector_type(4))) float f32x4;
typedef __attribute__((ext_vector_type(8))) short short8;

// ---------------- geometry ----------------
#define NB 8
#define NC 512
#define HP 66
#define WP 66
#define NPOS 32768
#define KTOT 4608
#define NKT 72           // K-tiles of 64

#define XP_ELEMS (NB*HP*WP*NC)
#define WR_ELEMS (NC*KTOT)
#define WC2_ELEMS (64*NC)
#define PROP_OFF 0
#define CLS_OFF  1179648
#define ANCH_OFF 1769472
#define A_PER_B  36864

__device__ __forceinline__ short bf16bits(float v) {
    __hip_bfloat16 b = __float2bfloat16(v);
    return *reinterpret_cast<short*>(&b);
}
__device__ __forceinline__ void gload16(const short* g, short* l) {
    __builtin_amdgcn_global_load_lds(
        (const __attribute__((address_space(1))) unsigned int*)g,
        (__attribute__((address_space(3))) unsigned int*)l, 16, 0, 0);
}
#define BARRIER() asm volatile("s_barrier" ::: "memory")
#define VMCNT4()  asm volatile("s_waitcnt vmcnt(4)" ::: "memory")
#define VMCNT0()  asm volatile("s_waitcnt vmcnt(0)" ::: "memory")

// ---------------- fused prep: input pack + weight packs + zero fills --------
// grid 5256: [0,4096) input; [4096,4608) conv_w; [4608,4736) Wc2; rest border
__global__ void prep_all(const float* __restrict__ x, const float* __restrict__ conv_w,
                         const float* __restrict__ cls_w, const float* __restrict__ reg_w,
                         short* __restrict__ Wr, short* __restrict__ Wc2,
                         short* __restrict__ Xp) {
    __shared__ float smem[4608];
    const int bid = blockIdx.x, tid = threadIdx.x;
    if (bid < 4096) {
        float (*t)[65] = (float(*)[65])smem;
        const int pb = bid & 63, cb = (bid >> 6) & 7, b = bid >> 9;
        const int tx = tid & 63, ty = tid >> 6;
        const float* src = x + ((size_t)(b*NC + cb*64))*4096 + pb*64;
#pragma unroll
        for (int r = 0; r < 16; ++r) {
            int ch = ty + r*4;
            t[ch][tx] = src[(size_t)ch*4096 + tx];
        }
        __syncthreads();
#pragma unroll
        for (int rr = 0; rr < 2; ++rr) {
            int item = tid + rr*256;
            int pl = item >> 3, ck = item & 7;
            short8 v;
#pragma unroll
            for (int e = 0; e < 8; ++e) v[e] = bf16bits(t[ck*8+e][pl]);
            *(short8*)&Xp[((size_t)((b*HP + pb + 1)*WP) + (pl + 1))*NC + cb*64 + ck*8] = v;
        }
    } else if (bid < 4608) {
        const int o = bid - 4096;
        const float* src = conv_w + (size_t)o*4608;
        for (int i = tid; i < 4608; i += 256) smem[i] = src[i];
        __syncthreads();
#pragma unroll
        for (int k = 0; k < 9; ++k)
#pragma unroll
            for (int c = 0; c < 2; ++c) {
                int ci = tid + c*256;
                Wr[(size_t)o*4608 + k*512 + ci] = bf16bits(smem[ci*9 + k]);
            }
    } else {
        const int m = bid - 4608;
        if (m < 128) {
            int t = m*256 + tid;
            int row = t >> 9, ci = t & 511;
            float v = 0.f;
            if (row < 18)      v = cls_w[row*NC + ci];
            else if (row < 54) v = reg_w[(row-18)*NC + ci];
            Wc2[t] = bf16bits(v);
        } else {
            int idx = (m-128)*256 + tid;          // < 133120
            int b = idx / 16640;
            int rem = idx - b*16640;
            int r = rem >> 6, g = rem & 63;
            int h, w;
            if      (r < 66)  { h = 0;       w = r; }
            else if (r < 132) { h = 65;      w = r - 66; }
            else if (r < 196) { h = r - 131; w = 0; }
            else              { h = r - 195; w = 65; }
            short8 z = (short8){0,0,0,0,0,0,0,0};
            *(short8*)&Xp[((size_t)((b*HP + h)*WP) + w)*NC + g*8] = z;
        }
    }
}

// ---------------- conv: 256^2-tile 8-phase + partial-K head epilogue --------
// K-loop identical to the round-2 kernel (135.9us / 50.5% MfmaUtil measured).
// Epilogue: acc -> swizzled LDS f_tile[256pos][256ch] bf16 -> head partial
// GEMM (M=256,N=64,K=256) -> f32 partials[half][pos][64] in ws. No f in HBM.
__launch_bounds__(512, 2)
__global__ void conv_fused(const short* __restrict__ Xp, const short* __restrict__ Wr,
                           const float* __restrict__ bias, const short* __restrict__ Wc2,
                           float* __restrict__ partial) {
    extern __shared__ short lds[];
    const int tid = threadIdx.x;
    const int lane = tid & 63, wv = tid >> 6;
    const int bid = blockIdx.x;
    const int wg = (bid & 7) * 32 + (bid >> 3);       // XCD swizzle (256%8==0)
    const int pbase  = (wg >> 1) * 256;
    const int cobase = (wg & 1) * 256;
    const int wm = wv >> 2, wn = wv & 3;

    const int g_data = (tid & 7) ^ ((tid >> 3) & 7);  // pre-swizzled k-group
    int abase[4], bbase[4];
#pragma unroll
    for (int q = 0; q < 4; ++q) {
        int p = pbase + q*64 + (tid >> 3);
        int b = p >> 12, h = (p >> 6) & 63, w = p & 63;
        abase[q] = ((b*HP + h)*WP + w)*NC + g_data*8;
        bbase[q] = (cobase + q*64 + (tid >> 3))*KTOT + g_data*8;
    }
    const int stoff = tid*8;

    const int l15 = lane & 15, l4 = lane >> 4, l7 = lane & 7;
    const int kidx0 = (l4 ^ l7) * 8;
    const int kidx1 = ((4 + l4) ^ l7) * 8;
    const int Aroff = wm*8192 + l15*64;
    const int Broff = 16384 + (wn>>1)*8192 + (wn&1)*4096 + l15*64;

    auto stageA = [&](int t, int hh) {
        int seg = t >> 3;
        int dh = seg / 3, dw = seg - dh*3;
        int off = (dh*WP + dw)*NC + (t & 7)*64;
        short* dst = lds + (t & 1)*32768 + hh*8192 + stoff;
        gload16(Xp + abase[hh*2+0] + off, dst);
        gload16(Xp + abase[hh*2+1] + off, dst + 4096);
    };
    auto stageB = [&](int t, int hh) {
        int off = t * 64;
        short* dst = lds + (t & 1)*32768 + 16384 + hh*8192 + stoff;
        gload16(Wr + bbase[hh*2+0] + off, dst);
        gload16(Wr + bbase[hh*2+1] + off, dst + 4096);
    };

    f32x4 acc[8][4];
#pragma unroll
    for (int i = 0; i < 8; ++i)
#pragma unroll
        for (int j = 0; j < 4; ++j) acc[i][j] = (f32x4){0.f,0.f,0.f,0.f};

    short8 af[2][2], bfr[4][2];
    auto readA = [&](int bufb, int i2) {
        const short* Ab = lds + bufb*32768 + Aroff;
#pragma unroll
        for (int ii = 0; ii < 2; ++ii) {
            af[ii][0] = *(const short8*)(Ab + (i2+ii)*1024 + kidx0);
            af[ii][1] = *(const short8*)(Ab + (i2+ii)*1024 + kidx1);
        }
    };
    auto readB = [&](int bufb) {
        const short* Bb = lds + bufb*32768 + Broff;
#pragma unroll
        for (int j = 0; j < 4; ++j) {
            bfr[j][0] = *(const short8*)(Bb + j*1024 + kidx0);
            bfr[j][1] = *(const short8*)(Bb + j*1024 + kidx1);
        }
    };
    auto mfmaQ = [&](int i2) {
        __builtin_amdgcn_s_setprio(1);
#pragma unroll
        for (int kk = 0; kk < 2; ++kk)
#pragma unroll
            for (int ii = 0; ii < 2; ++ii)
#pragma unroll
                for (int j = 0; j < 4; ++j)
                    acc[i2+ii][j] = __builtin_amdgcn_mfma_f32_16x16x32_bf16(
                        af[ii][kk], bfr[j][kk], acc[i2+ii][j], 0, 0, 0);
        __builtin_amdgcn_s_setprio(0);
    };

    // prologue
    stageB(0,0); stageB(0,1); stageA(0,0); stageA(0,1); stageB(1,0); stageB(1,1);
    VMCNT4(); BARRIER();

    for (int it = 0; it < 36; ++it) {
        const int t1 = 2*it+1, t2 = 2*it+2, t3 = 2*it+3;
        const bool s2 = (t2 < NKT), s3 = (t3 < NKT);
        readB(0); readA(0, 0);
        stageA(t1, 0);
        BARRIER(); mfmaQ(0); BARRIER();
        readA(0, 2);
        stageA(t1, 1);
        BARRIER(); mfmaQ(2); BARRIER();
        readA(0, 4);
        if (s2) stageB(t2, 0);
        BARRIER(); mfmaQ(4); BARRIER();
        readA(0, 6);
        if (s2) stageB(t2, 1);
        BARRIER(); mfmaQ(6);
        if (s2) { VMCNT4(); } else { VMCNT0(); }
        BARRIER();
        readB(1); readA(1, 0);
        if (s2) stageA(t2, 0);
        BARRIER(); mfmaQ(0); BARRIER();
        readA(1, 2);
        if (s2) stageA(t2, 1);
        BARRIER(); mfmaQ(2); BARRIER();
        readA(1, 4);
        if (s3) stageB(t3, 0);
        BARRIER(); mfmaQ(4); BARRIER();
        readA(1, 6);
        if (s3) stageB(t3, 1);
        BARRIER(); mfmaQ(6);
        if (s3) { VMCNT4(); } else { VMCNT0(); }
        BARRIER();
    }
    __syncthreads();

    // ---- ep1: bias+relu -> f_tile[256][256] bf16, XOR-swizzled (128KB LDS)
    // D frag: col = l15 (ch), row = l4*4 + r (pos)
#pragma unroll
    for (int j = 0; j < 4; ++j) {
        const int ch = wn*64 + j*16 + l15;            // local ch 0..255
        const float bb = bias[cobase + ch];
        const int g = ch >> 3, e = ch & 7;
#pragma unroll
        for (int i = 0; i < 8; ++i) {
#pragma unroll
            for (int r = 0; r < 4; ++r) {
                const int pos = wm*128 + i*16 + l4*4 + r;
                float v = acc[i][j][r] + bb;
                v = v > 0.f ? v : 0.f;
                const int slot = (g & 24) | ((g ^ pos) & 7);
                lds[pos*256 + slot*8 + e] = bf16bits(v);
            }
        }
    }
    __syncthreads();

    // ---- ep2: head partial GEMM M=256(pos), N=64, K=256(local ch)
    f32x4 acc2[2][4];
#pragma unroll
    for (int i2 = 0; i2 < 2; ++i2)
#pragma unroll
        for (int j2 = 0; j2 < 4; ++j2) acc2[i2][j2] = (f32x4){0.f,0.f,0.f,0.f};
    const int hbase = wv*32;
#pragma unroll
    for (int kk = 0; kk < 8; ++kk) {
        short8 b2[4];
#pragma unroll
        for (int j2 = 0; j2 < 4; ++j2)
            b2[j2] = *(const short8*)&Wc2[(size_t)(j2*16 + l15)*NC + cobase + kk*32 + l4*8];
#pragma unroll
        for (int i2 = 0; i2 < 2; ++i2) {
            const int pos = hbase + i2*16 + l15;
            const int g = kk*4 + l4;
            const int slot = (g & 24) | ((g ^ pos) & 7);
            short8 a2 = *(const short8*)&lds[pos*256 + slot*8];
#pragma unroll
            for (int j2 = 0; j2 < 4; ++j2)
                acc2[i2][j2] = __builtin_amdgcn_mfma_f32_16x16x32_bf16(
                    a2, b2[j2], acc2[i2][j2], 0, 0, 0);
        }
    }

    // ---- ep3: write partials[half][pos][64] f32
    const int half = wg & 1;
    float* pdst = partial + ((size_t)half*NPOS + pbase + hbase)*64;
#pragma unroll
    for (int i2 = 0; i2 < 2; ++i2)
#pragma unroll
        for (int j2 = 0; j2 < 4; ++j2)
#pragma unroll
            for (int r = 0; r < 4; ++r)
                pdst[(i2*16 + l4*4 + r)*64 + j2*16 + l15] = acc2[i2][j2][r];
}

// ---------------- combine: sum K-halves + anchor decode + anchors zeros -----
__device__ const float AW_T[9] = {
    181.01933598375618f, 362.03867196751236f, 724.0773439350247f,
    128.f, 256.f, 512.f,
    90.50966799187809f, 181.01933598375618f, 362.03867196751236f };
__device__ const float AH_T[9] = {
    90.50966799187809f, 181.01933598375618f, 362.03867196751236f,
    128.f, 256.f, 512.f,
    181.01933598375618f, 362.03867196751236f, 724.0773439350247f };

__launch_bounds__(256)
__global__ void combine_decode(const float* __restrict__ partial,
                               const float* __restrict__ cls_b, const float* __restrict__ reg_b,
                               const int* __restrict__ img, float* __restrict__ out) {
    __shared__ float sm[64*65];
    const int tid = threadIdx.x;
    const int p0 = blockIdx.x * 64;
    const float4* pa = (const float4*)partial;
#pragma unroll
    for (int q = 0; q < 4; ++q) {
        int idx = tid + q*256;                 // 1024 = 64 pos x 16 float4
        int pl = idx >> 4, n4 = idx & 15;
        float4 a = pa[(size_t)(p0 + pl)*16 + n4];
        float4 b = pa[(size_t)(NPOS + p0 + pl)*16 + n4];
        sm[pl*65 + n4*4 + 0] = a.x + b.x;
        sm[pl*65 + n4*4 + 1] = a.y + b.y;
        sm[pl*65 + n4*4 + 2] = a.z + b.z;
        sm[pl*65 + n4*4 + 3] = a.w + b.w;
    }
    __syncthreads();

    for (int item = tid; item < 576; item += 256) {
        int pl = item / 9, a = item - pl*9;
        int p = p0 + pl;
        int b = p >> 12, h = (p >> 6) & 63, w = p & 63;
        float c0 = sm[pl*65 + a*2 + 0] + cls_b[a*2 + 0];
        float c1 = sm[pl*65 + a*2 + 1] + cls_b[a*2 + 1];
        float r0 = sm[pl*65 + 18 + a*4 + 0] + reg_b[a*4 + 0];
        float r1 = sm[pl*65 + 18 + a*4 + 1] + reg_b[a*4 + 1];
        float r2 = sm[pl*65 + 18 + a*4 + 2] + reg_b[a*4 + 2];
        float r3 = sm[pl*65 + 18 + a*4 + 3] + reg_b[a*4 + 3];
        float aw = AW_T[a], ah = AH_T[a];
        float ax = 8.f + 16.f*w, ay = 8.f + 16.f*h;
        float px = ax + r0*aw,  py = ay + r1*ah;
        float pw = aw*__expf(r2), ph = ah*__expf(r3);
        float imw = (float)img[b*2 + 0], imh = (float)img[b*2 + 1];
        float x1 = fminf(fmaxf(px - 0.5f*pw, 0.f), imw);
        float y1 = fminf(fmaxf(py - 0.5f*ph, 0.f), imh);
        float x2 = fminf(fmaxf(px + 0.5f*pw, 0.f), imw);
        float y2 = fminf(fmaxf(py + 0.5f*ph, 0.f), imh);
        int ag = (h*64 + w)*9 + a;
        float4* prop = (float4*)(out + PROP_OFF + ((size_t)b*A_PER_B + ag)*4);
        *prop = make_float4(x1, y1, x2, y2);
        float2* cs = (float2*)(out + CLS_OFF + ((size_t)b*A_PER_B + ag)*2);
        *cs = make_float2(c0, c1);
        out[ANCH_OFF + (size_t)b*A_PER_B + ag] = 0.0f;   // anchors_ignore = 0
    }
}

extern "C" void kernel_launch(void* const* d_in, const int* in_sizes, int n_in,
                              void* d_out, int out_size, void* d_ws, size_t ws_size,
                              hipStream_t stream) {
    const float* x      = (const float*)d_in[0];
    const int*   img    = (const int*)  d_in[1];
    const float* conv_w = (const float*)d_in[2];
    const float* conv_b = (const float*)d_in[3];
    const float* cls_w  = (const float*)d_in[4];
    const float* cls_b  = (const float*)d_in[5];
    const float* reg_w  = (const float*)d_in[6];
    const float* reg_b  = (const float*)d_in[7];
    float* out = (float*)d_out;

    short* Xp      = (short*)d_ws;
    short* Wr      = Xp  + XP_ELEMS;
    short* Wc2     = Wr  + WR_ELEMS;
    float* partial = (float*)(Wc2 + WC2_ELEMS);   // 2*NPOS*64 f32 = 16MB

    prep_all<<<5256, 256, 0, stream>>>(x, conv_w, cls_w, reg_w, Wr, Wc2, Xp);

    hipFuncSetAttribute((const void*)conv_fused,
                        hipFuncAttributeMaxDynamicSharedMemorySize, 131072);
    conv_fused<<<256, 512, 131072, stream>>>(Xp, Wr, conv_b, Wc2, partial);
    combine_decode<<<NPOS/64, 256, 0, stream>>>(partial, cls_b, reg_b, img, out);
}